// Round 2
// baseline (756.693 us; speedup 1.0000x reference)
//
#include <hip/hip_runtime.h>
#include <hip/hip_bf16.h>

#define E_ 8
#define H_ 2048
#define I_ 1024
#define T_ 16384
#define BK 64
#define BM 256
#define MT_ (T_ / BM + E_)   // 72 max m-tiles (64 full + up to 8 partial)
#define SLOT 32768           // ushorts per LDS slot (64 KB); 2 slots = 128 KB

typedef __bf16 bf16x8 __attribute__((ext_vector_type(8)));
typedef float f32x4 __attribute__((ext_vector_type(4)));

__device__ __forceinline__ unsigned short f2bf(float f) {
  unsigned int x = __float_as_uint(f);
  x += 0x7FFFu + ((x >> 16) & 1u);   // round-to-nearest-even
  return (unsigned short)(x >> 16);
}

__device__ __forceinline__ void gl_lds16(const void* g, void* s) {
  __builtin_amdgcn_global_load_lds(
      (const __attribute__((address_space(1))) void*)g,
      (__attribute__((address_space(3))) void*)s, 16, 0, 0);
}

// Counted waits: never drain to 0 in the main loop (T4).
#define VMCNT2 asm volatile("s_waitcnt vmcnt(2)" ::: "memory")
#define VMCNT4 asm volatile("s_waitcnt vmcnt(4)" ::: "memory")
// Raw barrier (no implicit vmcnt(0) drain) + scheduling fence so following
// ds_reads can't be hoisted above the publication point.
#define BARRIER                        \
  do {                                 \
    __builtin_amdgcn_s_barrier();      \
    __builtin_amdgcn_sched_barrier(0); \
  } while (0)

// 16-MFMA phase cluster wrapped in setprio (T5)
#define MFMA16(ACC, AF, BF)                                                     \
  do {                                                                          \
    __builtin_amdgcn_s_setprio(1);                                              \
    _Pragma("unroll") for (int ks = 0; ks < 2; ks++)                            \
    _Pragma("unroll") for (int mi = 0; mi < 4; mi++)                            \
    _Pragma("unroll") for (int ni = 0; ni < 2; ni++)                            \
      ACC[mi][ni] = __builtin_amdgcn_mfma_f32_16x16x32_bf16(                    \
          AF[mi][ks], BF[ni][ks], ACC[mi][ni], 0, 0, 0);                        \
    __builtin_amdgcn_s_setprio(0);                                              \
  } while (0)

__device__ __forceinline__ bool find_tile(const int* gs, int tile, int& e,
                                          int& row0, int& rowEnd) {
  int base = 0, tb = 0;
  e = -1;
  for (int i = 0; i < E_; i++) {
    int g = gs[i];
    int nt = (g + BM - 1) >> 8;
    if (e < 0 && tile < tb + nt) {
      e = i;
      row0 = base + (tile - tb) * BM;
      rowEnd = base + g;
    }
    tb += nt;
    base += g;
  }
  return e >= 0;
}

// ---------------- conversion kernels (unchanged) ----------------

__global__ void cvt_hs(const float* __restrict__ in, ushort* __restrict__ out) {
  size_t i = ((size_t)blockIdx.x * 256 + threadIdx.x) * 8;
  float4 a = *(const float4*)(in + i);
  float4 b = *(const float4*)(in + i + 4);
  union { ushort u[8]; uint4 v; } p;
  p.u[0] = f2bf(a.x); p.u[1] = f2bf(a.y); p.u[2] = f2bf(a.z); p.u[3] = f2bf(a.w);
  p.u[4] = f2bf(b.x); p.u[5] = f2bf(b.y); p.u[6] = f2bf(b.z); p.u[7] = f2bf(b.w);
  *(uint4*)(out + i) = p.v;
}

__global__ void cvt_tr(const float* __restrict__ in, ushort* __restrict__ out,
                       int K, int N) {
  __shared__ ushort tile[64][65];
  int n0 = blockIdx.x * 64, k0 = blockIdx.y * 64;
  const float* src = in + (size_t)blockIdx.z * K * N;
  ushort* dst = out + (size_t)blockIdx.z * K * N;
  int t = threadIdx.x;
  int rb = t >> 4, c4 = (t & 15) * 4;
#pragma unroll
  for (int i = 0; i < 4; i++) {
    int r = rb + i * 16;
    float4 v = *(const float4*)(src + (size_t)(k0 + r) * N + n0 + c4);
    tile[r][c4 + 0] = f2bf(v.x);
    tile[r][c4 + 1] = f2bf(v.y);
    tile[r][c4 + 2] = f2bf(v.z);
    tile[r][c4 + 3] = f2bf(v.w);
  }
  __syncthreads();
#pragma unroll
  for (int i = 0; i < 2; i++) {
    int c = t + i * 256;
    int n = c >> 3, kc = c & 7;
    union { ushort u[8]; uint4 v; } p;
#pragma unroll
    for (int j = 0; j < 8; j++) p.u[j] = tile[kc * 8 + j][n];
    *(uint4*)(dst + (size_t)(n0 + n) * K + k0 + kc * 8) = p.v;
  }
}

// ---------------- fused gate/up GEMM + SwiGLU: 256x128 tile, 8 waves ----------------
// One-phase-ahead ds_read pipeline. Per phase:
//   vmcnt(2) [retire unit read THIS phase] -> barrier -> stage 1 unit of t+1
//   -> ds_read NEXT phase's fragments -> 16 MFMA on fragments read LAST phase.
// Stage order A-lo, G, U, A-hi. MFMA order: G*lo, U*lo, G*hi, U*hi (M0 and M3
// share no fragments, so P3's cross-tile reads of {A-lo,G}(t+1) never WAR).
__global__ __launch_bounds__(512, 2) void gemm_gateup(
    const ushort* __restrict__ A, const ushort* __restrict__ BgT,
    const ushort* __restrict__ BuT, const int* __restrict__ gs,
    ushort* __restrict__ Hb) {
  extern __shared__ __align__(16) ushort ls[];

  int e, row0, rowEnd;
  if (!find_tile(gs, blockIdx.x, e, row0, rowEnd)) return;
  const int n0 = blockIdx.y * 128;

  const int t = threadIdx.x;
  const int lane = t & 63;
  const int w = t >> 6;
  const int wm = w & 1, wn = w >> 1;  // 2M x 4N wave grid
  const int ldW = w * 512;

  int oAlo[2], oAhi[2], oB[2];
#pragma unroll
  for (int l = 0; l < 2; l++) {
    int c = l * 512 + t;
    int r = c >> 3, kc = (c & 7) ^ (r & 7);
    int a0 = row0 + r;       if (a0 > T_ - 1) a0 = T_ - 1;
    int a1 = row0 + 128 + r; if (a1 > T_ - 1) a1 = T_ - 1;
    oAlo[l] = a0 * H_ + kc * 8;
    oAhi[l] = a1 * H_ + kc * 8;
    oB[l] = (e * I_ + n0 + r) * H_ + kc * 8;
  }

  const int l15 = lane & 15, l7 = lane & 7, lk = lane >> 4;
  const int s0 = (lk ^ l7) * 8, s1 = ((lk + 4) ^ l7) * 8;
  const int arow = (wm * 64 + l15) * 64;
  const int brow = (wn * 32 + l15) * 64;

  f32x4 accG0[4][2], accG1[4][2], accU0[4][2], accU1[4][2];
#pragma unroll
  for (int mi = 0; mi < 4; mi++)
#pragma unroll
    for (int ni = 0; ni < 2; ni++) {
      accG0[mi][ni] = (f32x4){0.f, 0.f, 0.f, 0.f};
      accG1[mi][ni] = (f32x4){0.f, 0.f, 0.f, 0.f};
      accU0[mi][ni] = (f32x4){0.f, 0.f, 0.f, 0.f};
      accU1[mi][ni] = (f32x4){0.f, 0.f, 0.f, 0.f};
    }

  // fragment registers, live across phases
  bf16x8 afL[4][2], afH[4][2], gf[2][2], uf[2][2];

  // prologue: stage tile 0 (order A-lo, G, U, A-hi), retire {A-lo,G}, read F0
  gl_lds16(A + oAlo[0], ls + 0 + ldW);
  gl_lds16(A + oAlo[1], ls + 4096 + ldW);
  gl_lds16(BgT + oB[0], ls + 16384 + ldW);
  gl_lds16(BgT + oB[1], ls + 16384 + 4096 + ldW);
  gl_lds16(BuT + oB[0], ls + 24576 + ldW);
  gl_lds16(BuT + oB[1], ls + 24576 + 4096 + ldW);
  gl_lds16(A + oAhi[0], ls + 8192 + ldW);
  gl_lds16(A + oAhi[1], ls + 8192 + 4096 + ldW);
  VMCNT4; BARRIER;
#pragma unroll
  for (int mi = 0; mi < 4; mi++) {
    afL[mi][0] = *(const bf16x8*)(ls + arow + mi * 1024 + s0);
    afL[mi][1] = *(const bf16x8*)(ls + arow + mi * 1024 + s1);
  }
#pragma unroll
  for (int ni = 0; ni < 2; ni++) {
    gf[ni][0] = *(const bf16x8*)(ls + 16384 + brow + ni * 1024 + s0);
    gf[ni][1] = *(const bf16x8*)(ls + 16384 + brow + ni * 1024 + s1);
  }

#pragma unroll 2
  for (int tt = 0; tt < H_ / BK; tt++) {
    const int p = tt & 1, q = p ^ 1;
    const ushort* sa = ls + p * SLOT;
    ushort* sq = ls + q * SLOT;
    const int kn = (tt + 1 < H_ / BK ? tt + 1 : tt) * BK;

    // ---- P0: retire U(t); stage A-lo(t+1); read uf; MFMA G x lo ----
    VMCNT2; BARRIER;
    gl_lds16(A + oAlo[0] + kn, sq + 0 + ldW);
    gl_lds16(A + oAlo[1] + kn, sq + 4096 + ldW);
#pragma unroll
    for (int ni = 0; ni < 2; ni++) {
      uf[ni][0] = *(const bf16x8*)(sa + 24576 + brow + ni * 1024 + s0);
      uf[ni][1] = *(const bf16x8*)(sa + 24576 + brow + ni * 1024 + s1);
    }
    MFMA16(accG0, afL, gf);

    // ---- P1: retire A-hi(t); stage G(t+1); read af-hi; MFMA U x lo ----
    VMCNT2; BARRIER;
    gl_lds16(BgT + oB[0] + kn, sq + 16384 + ldW);
    gl_lds16(BgT + oB[1] + kn, sq + 16384 + 4096 + ldW);
#pragma unroll
    for (int mi = 0; mi < 4; mi++) {
      afH[mi][0] = *(const bf16x8*)(sa + 8192 + arow + mi * 1024 + s0);
      afH[mi][1] = *(const bf16x8*)(sa + 8192 + arow + mi * 1024 + s1);
    }
    MFMA16(accU0, afL, uf);

    // ---- P2: stage U(t+1); MFMA G x hi (no new reads) ----
    BARRIER;
    gl_lds16(BuT + oB[0] + kn, sq + 24576 + ldW);
    gl_lds16(BuT + oB[1] + kn, sq + 24576 + 4096 + ldW);
    MFMA16(accG1, afH, gf);

    // ---- P3: retire {A-lo,G}(t+1); stage A-hi(t+1); read F0(t+1); MFMA U x hi ----
    VMCNT2; BARRIER;
    gl_lds16(A + oAhi[0] + kn, sq + 8192 + ldW);
    gl_lds16(A + oAhi[1] + kn, sq + 8192 + 4096 + ldW);
#pragma unroll
    for (int mi = 0; mi < 4; mi++) {
      afL[mi][0] = *(const bf16x8*)(sq + arow + mi * 1024 + s0);
      afL[mi][1] = *(const bf16x8*)(sq + arow + mi * 1024 + s1);
    }
#pragma unroll
    for (int ni = 0; ni < 2; ni++) {
      gf[ni][0] = *(const bf16x8*)(sq + 16384 + brow + ni * 1024 + s0);
      gf[ni][1] = *(const bf16x8*)(sq + 16384 + brow + ni * 1024 + s1);
    }
    MFMA16(accU1, afH, uf);
  }

  // epilogue: h = silu(g)*u, bf16 store. C/D: col=lane&15, row=(lane>>4)*4+r
  const int cr = row0 + wm * 64 + (lk << 2);
  const int cc = n0 + wn * 32 + l15;
#pragma unroll
  for (int mh = 0; mh < 2; mh++)
#pragma unroll
    for (int mi = 0; mi < 4; mi++)
#pragma unroll
      for (int ni = 0; ni < 2; ni++)
#pragma unroll
        for (int r = 0; r < 4; r++) {
          int row = cr + mh * 128 + mi * 16 + r;
          if (row < rowEnd) {
            float g = mh ? accG1[mi][ni][r] : accG0[mi][ni][r];
            float u = mh ? accU1[mi][ni][r] : accU0[mi][ni][r];
            float h = (g / (1.0f + __expf(-g))) * u;
            Hb[(size_t)row * I_ + cc + ni * 16] = f2bf(h);
          }
        }
}

// ---------------- down GEMM: 256x256 tile, 8 waves ----------------
// Same one-phase-ahead pipeline. Stage order A-lo, B-lo, B-hi, A-hi.
// Quadrant order M0=(0,0) M1=(0,1) M2=(1,0) M3=(1,1): M0/M3 disjoint so
// P3's cross-tile reads of {A-lo,B-lo}(t+1) never WAR a live fragment.
__global__ __launch_bounds__(512, 2) void gemm_down(
    const ushort* __restrict__ A, const ushort* __restrict__ BdT,
    const int* __restrict__ gs, float* __restrict__ Out) {
  extern __shared__ __align__(16) ushort ls[];

  int e, row0, rowEnd;
  if (!find_tile(gs, blockIdx.x, e, row0, rowEnd)) return;
  const int n0 = blockIdx.y * 256;

  const int t = threadIdx.x;
  const int lane = t & 63;
  const int w = t >> 6;
  const int wm = w & 1, wn = w >> 1;
  const int ldW = w * 512;

  int oAlo[2], oAhi[2], oBlo[2], oBhi[2];
#pragma unroll
  for (int l = 0; l < 2; l++) {
    int c = l * 512 + t;
    int r = c >> 3, kc = (c & 7) ^ (r & 7);
    int a0 = row0 + r;       if (a0 > T_ - 1) a0 = T_ - 1;
    int a1 = row0 + 128 + r; if (a1 > T_ - 1) a1 = T_ - 1;
    oAlo[l] = a0 * I_ + kc * 8;
    oAhi[l] = a1 * I_ + kc * 8;
    oBlo[l] = (e * H_ + n0 + r) * I_ + kc * 8;
    oBhi[l] = (e * H_ + n0 + 128 + r) * I_ + kc * 8;
  }

  const int l15 = lane & 15, l7 = lane & 7, lk = lane >> 4;
  const int s0 = (lk ^ l7) * 8, s1 = ((lk + 4) ^ l7) * 8;
  const int arow = (wm * 64 + l15) * 64;
  const int brow = (wn * 32 + l15) * 64;

  f32x4 acc00[4][2], acc01[4][2], acc10[4][2], acc11[4][2];  // [mh][nh]
#pragma unroll
  for (int mi = 0; mi < 4; mi++)
#pragma unroll
    for (int ni = 0; ni < 2; ni++) {
      acc00[mi][ni] = (f32x4){0.f, 0.f, 0.f, 0.f};
      acc01[mi][ni] = (f32x4){0.f, 0.f, 0.f, 0.f};
      acc10[mi][ni] = (f32x4){0.f, 0.f, 0.f, 0.f};
      acc11[mi][ni] = (f32x4){0.f, 0.f, 0.f, 0.f};
    }

  bf16x8 afL[4][2], afH[4][2], bfL[2][2], bfH[2][2];

  // prologue: tile 0, order A-lo, B-lo, B-hi, A-hi; retire {A-lo,B-lo}; read F0
  gl_lds16(A + oAlo[0], ls + 0 + ldW);
  gl_lds16(A + oAlo[1], ls + 4096 + ldW);
  gl_lds16(BdT + oBlo[0], ls + 16384 + ldW);
  gl_lds16(BdT + oBlo[1], ls + 16384 + 4096 + ldW);
  gl_lds16(BdT + oBhi[0], ls + 24576 + ldW);
  gl_lds16(BdT + oBhi[1], ls + 24576 + 4096 + ldW);
  gl_lds16(A + oAhi[0], ls + 8192 + ldW);
  gl_lds16(A + oAhi[1], ls + 8192 + 4096 + ldW);
  VMCNT4; BARRIER;
#pragma unroll
  for (int mi = 0; mi < 4; mi++) {
    afL[mi][0] = *(const bf16x8*)(ls + arow + mi * 1024 + s0);
    afL[mi][1] = *(const bf16x8*)(ls + arow + mi * 1024 + s1);
  }
#pragma unroll
  for (int ni = 0; ni < 2; ni++) {
    bfL[ni][0] = *(const bf16x8*)(ls + 16384 + brow + ni * 1024 + s0);
    bfL[ni][1] = *(const bf16x8*)(ls + 16384 + brow + ni * 1024 + s1);
  }

#pragma unroll 2
  for (int tt = 0; tt < I_ / BK; tt++) {
    const int p = tt & 1, q = p ^ 1;
    const ushort* sa = ls + p * SLOT;
    ushort* sq = ls + q * SLOT;
    const int kn = (tt + 1 < I_ / BK ? tt + 1 : tt) * BK;

    // ---- P0: retire B-hi(t); stage A-lo(t+1); read bf-hi; MFMA (0,0) ----
    VMCNT2; BARRIER;
    gl_lds16(A + oAlo[0] + kn, sq + 0 + ldW);
    gl_lds16(A + oAlo[1] + kn, sq + 4096 + ldW);
#pragma unroll
    for (int ni = 0; ni < 2; ni++) {
      bfH[ni][0] = *(const bf16x8*)(sa + 24576 + brow + ni * 1024 + s0);
      bfH[ni][1] = *(const bf16x8*)(sa + 24576 + brow + ni * 1024 + s1);
    }
    MFMA16(acc00, afL, bfL);

    // ---- P1: retire A-hi(t); stage B-lo(t+1); read af-hi; MFMA (0,1) ----
    VMCNT2; BARRIER;
    gl_lds16(BdT + oBlo[0] + kn, sq + 16384 + ldW);
    gl_lds16(BdT + oBlo[1] + kn, sq + 16384 + 4096 + ldW);
#pragma unroll
    for (int mi = 0; mi < 4; mi++) {
      afH[mi][0] = *(const bf16x8*)(sa + 8192 + arow + mi * 1024 + s0);
      afH[mi][1] = *(const bf16x8*)(sa + 8192 + arow + mi * 1024 + s1);
    }
    MFMA16(acc01, afL, bfH);

    // ---- P2: stage B-hi(t+1); MFMA (1,0) (no new reads) ----
    BARRIER;
    gl_lds16(BdT + oBhi[0] + kn, sq + 24576 + ldW);
    gl_lds16(BdT + oBhi[1] + kn, sq + 24576 + 4096 + ldW);
    MFMA16(acc10, afH, bfL);

    // ---- P3: retire {A-lo,B-lo}(t+1); stage A-hi(t+1); read F0(t+1); MFMA (1,1) ----
    VMCNT2; BARRIER;
    gl_lds16(A + oAhi[0] + kn, sq + 8192 + ldW);
    gl_lds16(A + oAhi[1] + kn, sq + 8192 + 4096 + ldW);
#pragma unroll
    for (int mi = 0; mi < 4; mi++) {
      afL[mi][0] = *(const bf16x8*)(sq + arow + mi * 1024 + s0);
      afL[mi][1] = *(const bf16x8*)(sq + arow + mi * 1024 + s1);
    }
#pragma unroll
    for (int ni = 0; ni < 2; ni++) {
      bfL[ni][0] = *(const bf16x8*)(sq + 16384 + brow + ni * 1024 + s0);
      bfL[ni][1] = *(const bf16x8*)(sq + 16384 + brow + ni * 1024 + s1);
    }
    MFMA16(acc11, afH, bfH);
  }

  const int cr = row0 + wm * 64 + (lk << 2);
  const int cc = n0 + wn * 32 + l15;
#pragma unroll
  for (int mh = 0; mh < 2; mh++)
#pragma unroll
    for (int mi = 0; mi < 4; mi++)
#pragma unroll
      for (int nh = 0; nh < 2; nh++)
#pragma unroll
        for (int ni = 0; ni < 2; ni++)
#pragma unroll
          for (int r = 0; r < 4; r++) {
            int row = cr + mh * 128 + mi * 16 + r;
            if (row < rowEnd) {
              float v = mh ? (nh ? acc11[mi][ni][r] : acc10[mi][ni][r])
                           : (nh ? acc01[mi][ni][r] : acc00[mi][ni][r]);
              Out[(size_t)row * H_ + cc + nh * 128 + ni * 16] = v;
            }
          }
}

extern "C" void kernel_launch(void* const* d_in, const int* in_sizes, int n_in,
                              void* d_out, int out_size, void* d_ws, size_t ws_size,
                              hipStream_t stream) {
  const float* hs = (const float*)d_in[0];
  const float* gw = (const float*)d_in[1];
  const float* uw = (const float*)d_in[2];
  const float* dw = (const float*)d_in[3];
  const int* gs = (const int*)d_in[4];
  float* out = (float*)d_out;

  ushort* hsb = (ushort*)d_ws;                       // [T,H]
  ushort* wgT = hsb + (size_t)T_ * H_;               // [E,I,H]
  ushort* wuT = wgT + (size_t)E_ * H_ * I_;          // [E,I,H]
  ushort* wdT = wuT + (size_t)E_ * H_ * I_;          // [E,H,I]
  ushort* hb  = wdT + (size_t)E_ * H_ * I_;          // [T,I]

  (void)hipFuncSetAttribute(reinterpret_cast<const void*>(gemm_gateup),
                            hipFuncAttributeMaxDynamicSharedMemorySize, 131072);
  (void)hipFuncSetAttribute(reinterpret_cast<const void*>(gemm_down),
                            hipFuncAttributeMaxDynamicSharedMemorySize, 131072);

  cvt_hs<<<((size_t)T_ * H_) / (256 * 8), 256, 0, stream>>>(hs, hsb);
  cvt_tr<<<dim3(I_ / 64, H_ / 64, E_), 256, 0, stream>>>(gw, wgT, H_, I_);
  cvt_tr<<<dim3(I_ / 64, H_ / 64, E_), 256, 0, stream>>>(uw, wuT, H_, I_);
  cvt_tr<<<dim3(H_ / 64, I_ / 64, E_), 256, 0, stream>>>(dw, wdT, I_, H_);

  gemm_gateup<<<dim3(MT_, I_ / 128), 512, 131072, stream>>>(hsb, wgT, wuT, gs, hb);
  gemm_down<<<dim3(MT_, H_ / 256), 512, 131072, stream>>>(hb, wdT, gs, out);
}

// Round 3
// 563.743 us; speedup vs baseline: 1.3423x; 1.3423x over previous
//
#include <hip/hip_runtime.h>
#include <hip/hip_bf16.h>

#define E_ 8
#define H_ 2048
#define I_ 1024
#define T_ 16384
#define BK 64
#define BM 256
#define MT_ (T_ / BM + E_)   // 72 max m-tiles (64 full + up to 8 partial)
#define SLOT 32768           // ushorts per LDS slot (64 KB); 2 slots = 128 KB

typedef __bf16 bf16x8 __attribute__((ext_vector_type(8)));
typedef float f32x4 __attribute__((ext_vector_type(4)));

__device__ __forceinline__ unsigned short f2bf(float f) {
  unsigned int x = __float_as_uint(f);
  x += 0x7FFFu + ((x >> 16) & 1u);   // round-to-nearest-even
  return (unsigned short)(x >> 16);
}

__device__ __forceinline__ void gl_lds16(const void* g, void* s) {
  __builtin_amdgcn_global_load_lds(
      (const __attribute__((address_space(1))) void*)g,
      (__attribute__((address_space(3))) void*)s, 16, 0, 0);
}

// Counted wait: queue never drains below 4 in the main loop (T4).
#define VMCNT4 asm volatile("s_waitcnt vmcnt(4)" ::: "memory")
// Barrier bracketed by sched fences: pins the phase's ds_reads/stages above it
// and the MFMA cluster below it (rule #18-adjacent; compiler still emits its
// own fine-grained lgkmcnt before the first MFMA operand use).
#define BAR                              \
  do {                                   \
    __builtin_amdgcn_sched_barrier(0);   \
    __builtin_amdgcn_s_barrier();        \
    __builtin_amdgcn_sched_barrier(0);   \
  } while (0)

// 16-MFMA phase cluster wrapped in setprio (T5)
#define MFMA16(ACC, AF, BF)                                                     \
  do {                                                                          \
    __builtin_amdgcn_s_setprio(1);                                              \
    _Pragma("unroll") for (int ks = 0; ks < 2; ks++)                            \
    _Pragma("unroll") for (int mi = 0; mi < 4; mi++)                            \
    _Pragma("unroll") for (int ni = 0; ni < 2; ni++)                            \
      ACC[mi][ni] = __builtin_amdgcn_mfma_f32_16x16x32_bf16(                    \
          AF[mi][ks], BF[ni][ks], ACC[mi][ni], 0, 0, 0);                        \
    __builtin_amdgcn_s_setprio(0);                                              \
  } while (0)

__device__ __forceinline__ bool find_tile(const int* gs, int tile, int& e,
                                          int& row0, int& rowEnd) {
  int base = 0, tb = 0;
  e = -1;
  for (int i = 0; i < E_; i++) {
    int g = gs[i];
    int nt = (g + BM - 1) >> 8;
    if (e < 0 && tile < tb + nt) {
      e = i;
      row0 = base + (tile - tb) * BM;
      rowEnd = base + g;
    }
    tb += nt;
    base += g;
  }
  return e >= 0;
}

// ---------------- conversion kernels (unchanged) ----------------

__global__ void cvt_hs(const float* __restrict__ in, ushort* __restrict__ out) {
  size_t i = ((size_t)blockIdx.x * 256 + threadIdx.x) * 8;
  float4 a = *(const float4*)(in + i);
  float4 b = *(const float4*)(in + i + 4);
  union { ushort u[8]; uint4 v; } p;
  p.u[0] = f2bf(a.x); p.u[1] = f2bf(a.y); p.u[2] = f2bf(a.z); p.u[3] = f2bf(a.w);
  p.u[4] = f2bf(b.x); p.u[5] = f2bf(b.y); p.u[6] = f2bf(b.z); p.u[7] = f2bf(b.w);
  *(uint4*)(out + i) = p.v;
}

__global__ void cvt_tr(const float* __restrict__ in, ushort* __restrict__ out,
                       int K, int N) {
  __shared__ ushort tile[64][65];
  int n0 = blockIdx.x * 64, k0 = blockIdx.y * 64;
  const float* src = in + (size_t)blockIdx.z * K * N;
  ushort* dst = out + (size_t)blockIdx.z * K * N;
  int t = threadIdx.x;
  int rb = t >> 4, c4 = (t & 15) * 4;
#pragma unroll
  for (int i = 0; i < 4; i++) {
    int r = rb + i * 16;
    float4 v = *(const float4*)(src + (size_t)(k0 + r) * N + n0 + c4);
    tile[r][c4 + 0] = f2bf(v.x);
    tile[r][c4 + 1] = f2bf(v.y);
    tile[r][c4 + 2] = f2bf(v.z);
    tile[r][c4 + 3] = f2bf(v.w);
  }
  __syncthreads();
#pragma unroll
  for (int i = 0; i < 2; i++) {
    int c = t + i * 256;
    int n = c >> 3, kc = c & 7;
    union { ushort u[8]; uint4 v; } p;
#pragma unroll
    for (int j = 0; j < 8; j++) p.u[j] = tile[kc * 8 + j][n];
    *(uint4*)(dst + (size_t)(n0 + n) * K + k0 + kc * 8) = p.v;
  }
}

// ---------------- fused gate/up GEMM + SwiGLU: 256x128 tile, 8 waves ----------------
// m201-shaped phases: {ds_read this phase's frags; stage 1 unit of t+1; BAR;
// MFMA; [vmcnt(4)]; BAR}. Read latency hides under barrier-arrival spread; all
// fragments are read and consumed within the same phase window (no cross-tile
// register carry -> no spill). Publication rule: each unit's vmcnt(4) sits
// before the barrier preceding the phase that reads it. Queue: 4..8, never <4.
//   P0: read afL,gf   stage Alo'  MFMA G*lo   vmcnt4 (retire U)
//   P1: read uf       stage G'    MFMA U*lo   vmcnt4 (retire Ahi)
//   P2: read afH      stage U'    MFMA G*hi
//   P3: (no reads)    stage Ahi'  MFMA U*hi   vmcnt4 (retire Alo',G')
__global__ __launch_bounds__(512, 2) void gemm_gateup(
    const ushort* __restrict__ A, const ushort* __restrict__ BgT,
    const ushort* __restrict__ BuT, const int* __restrict__ gs,
    ushort* __restrict__ Hb) {
  extern __shared__ __align__(16) ushort ls[];

  int e, row0, rowEnd;
  if (!find_tile(gs, blockIdx.x, e, row0, rowEnd)) return;
  const int n0 = blockIdx.y * 128;

  const int t = threadIdx.x;
  const int lane = t & 63;
  const int w = t >> 6;
  const int wm = w & 1, wn = w >> 1;  // 2M x 4N wave grid
  const int ldW = w * 512;

  int oAlo[2], oAhi[2], oB[2];
#pragma unroll
  for (int l = 0; l < 2; l++) {
    int c = l * 512 + t;
    int r = c >> 3, kc = (c & 7) ^ (r & 7);
    int a0 = row0 + r;       if (a0 > T_ - 1) a0 = T_ - 1;
    int a1 = row0 + 128 + r; if (a1 > T_ - 1) a1 = T_ - 1;
    oAlo[l] = a0 * H_ + kc * 8;
    oAhi[l] = a1 * H_ + kc * 8;
    oB[l] = (e * I_ + n0 + r) * H_ + kc * 8;
  }

  const int l15 = lane & 15, l7 = lane & 7, lk = lane >> 4;
  const int s0 = (lk ^ l7) * 8, s1 = ((lk + 4) ^ l7) * 8;
  const int arow = (wm * 64 + l15) * 64;
  const int brow = (wn * 32 + l15) * 64;

  f32x4 accG0[4][2], accG1[4][2], accU0[4][2], accU1[4][2];
#pragma unroll
  for (int mi = 0; mi < 4; mi++)
#pragma unroll
    for (int ni = 0; ni < 2; ni++) {
      accG0[mi][ni] = (f32x4){0.f, 0.f, 0.f, 0.f};
      accG1[mi][ni] = (f32x4){0.f, 0.f, 0.f, 0.f};
      accU0[mi][ni] = (f32x4){0.f, 0.f, 0.f, 0.f};
      accU1[mi][ni] = (f32x4){0.f, 0.f, 0.f, 0.f};
    }

  // prologue: stage tile 0 (order Alo, G, U, Ahi); publish {Alo, G}
  gl_lds16(A + oAlo[0], ls + 0 + ldW);
  gl_lds16(A + oAlo[1], ls + 4096 + ldW);
  gl_lds16(BgT + oB[0], ls + 16384 + ldW);
  gl_lds16(BgT + oB[1], ls + 16384 + 4096 + ldW);
  gl_lds16(BuT + oB[0], ls + 24576 + ldW);
  gl_lds16(BuT + oB[1], ls + 24576 + 4096 + ldW);
  gl_lds16(A + oAhi[0], ls + 8192 + ldW);
  gl_lds16(A + oAhi[1], ls + 8192 + 4096 + ldW);
  VMCNT4; BAR;

#pragma unroll 2
  for (int tt = 0; tt < H_ / BK; tt++) {
    const int p = tt & 1, q = p ^ 1;
    const ushort* sa = ls + p * SLOT;
    ushort* sq = ls + q * SLOT;
    const int kn = (tt + 1 < H_ / BK ? tt + 1 : tt) * BK;
    bf16x8 afL[4][2], afH[4][2], gf[2][2], uf[2][2];

    // ---- P0 ----
#pragma unroll
    for (int mi = 0; mi < 4; mi++) {
      afL[mi][0] = *(const bf16x8*)(sa + arow + mi * 1024 + s0);
      afL[mi][1] = *(const bf16x8*)(sa + arow + mi * 1024 + s1);
    }
#pragma unroll
    for (int ni = 0; ni < 2; ni++) {
      gf[ni][0] = *(const bf16x8*)(sa + 16384 + brow + ni * 1024 + s0);
      gf[ni][1] = *(const bf16x8*)(sa + 16384 + brow + ni * 1024 + s1);
    }
    gl_lds16(A + oAlo[0] + kn, sq + 0 + ldW);
    gl_lds16(A + oAlo[1] + kn, sq + 4096 + ldW);
    BAR;
    MFMA16(accG0, afL, gf);
    VMCNT4; BAR;

    // ---- P1 ----
#pragma unroll
    for (int ni = 0; ni < 2; ni++) {
      uf[ni][0] = *(const bf16x8*)(sa + 24576 + brow + ni * 1024 + s0);
      uf[ni][1] = *(const bf16x8*)(sa + 24576 + brow + ni * 1024 + s1);
    }
    gl_lds16(BgT + oB[0] + kn, sq + 16384 + ldW);
    gl_lds16(BgT + oB[1] + kn, sq + 16384 + 4096 + ldW);
    BAR;
    MFMA16(accU0, afL, uf);
    VMCNT4; BAR;

    // ---- P2 + P3 (merged tail: P3 has no reads) ----
#pragma unroll
    for (int mi = 0; mi < 4; mi++) {
      afH[mi][0] = *(const bf16x8*)(sa + 8192 + arow + mi * 1024 + s0);
      afH[mi][1] = *(const bf16x8*)(sa + 8192 + arow + mi * 1024 + s1);
    }
    gl_lds16(BuT + oB[0] + kn, sq + 24576 + ldW);
    gl_lds16(BuT + oB[1] + kn, sq + 24576 + 4096 + ldW);
    BAR;
    MFMA16(accG1, afH, gf);
    gl_lds16(A + oAhi[0] + kn, sq + 8192 + ldW);
    gl_lds16(A + oAhi[1] + kn, sq + 8192 + 4096 + ldW);
    MFMA16(accU1, afH, uf);
    VMCNT4; BAR;
  }

  // epilogue: h = silu(g)*u, bf16 store. C/D: col=lane&15, row=(lane>>4)*4+r
  const int cr = row0 + wm * 64 + (lk << 2);
  const int cc = n0 + wn * 32 + l15;
#pragma unroll
  for (int mh = 0; mh < 2; mh++)
#pragma unroll
    for (int mi = 0; mi < 4; mi++)
#pragma unroll
      for (int ni = 0; ni < 2; ni++)
#pragma unroll
        for (int r = 0; r < 4; r++) {
          int row = cr + mh * 128 + mi * 16 + r;
          if (row < rowEnd) {
            float g = mh ? accG1[mi][ni][r] : accG0[mi][ni][r];
            float u = mh ? accU1[mi][ni][r] : accU0[mi][ni][r];
            float h = (g / (1.0f + __expf(-g))) * u;
            Hb[(size_t)row * I_ + cc + ni * 16] = f2bf(h);
          }
        }
}

// ---------------- down GEMM: 256x256 tile, 8 waves ----------------
// Same phase shape. Stage order Alo, Blo, Bhi, Ahi.
//   P0: read afL,bfL  stage Alo'  MFMA (0,0)  vmcnt4 (retire Bhi)
//   P1: read bfH      stage Blo'  MFMA (0,1)  vmcnt4 (retire Ahi)
//   P2: read afH      stage Bhi'  MFMA (1,0)
//   P3: (no reads)    stage Ahi'  MFMA (1,1)  vmcnt4 (retire Alo',Blo')
__global__ __launch_bounds__(512, 2) void gemm_down(
    const ushort* __restrict__ A, const ushort* __restrict__ BdT,
    const int* __restrict__ gs, float* __restrict__ Out) {
  extern __shared__ __align__(16) ushort ls[];

  int e, row0, rowEnd;
  if (!find_tile(gs, blockIdx.x, e, row0, rowEnd)) return;
  const int n0 = blockIdx.y * 256;

  const int t = threadIdx.x;
  const int lane = t & 63;
  const int w = t >> 6;
  const int wm = w & 1, wn = w >> 1;
  const int ldW = w * 512;

  int oAlo[2], oAhi[2], oBlo[2], oBhi[2];
#pragma unroll
  for (int l = 0; l < 2; l++) {
    int c = l * 512 + t;
    int r = c >> 3, kc = (c & 7) ^ (r & 7);
    int a0 = row0 + r;       if (a0 > T_ - 1) a0 = T_ - 1;
    int a1 = row0 + 128 + r; if (a1 > T_ - 1) a1 = T_ - 1;
    oAlo[l] = a0 * I_ + kc * 8;
    oAhi[l] = a1 * I_ + kc * 8;
    oBlo[l] = (e * H_ + n0 + r) * I_ + kc * 8;
    oBhi[l] = (e * H_ + n0 + 128 + r) * I_ + kc * 8;
  }

  const int l15 = lane & 15, l7 = lane & 7, lk = lane >> 4;
  const int s0 = (lk ^ l7) * 8, s1 = ((lk + 4) ^ l7) * 8;
  const int arow = (wm * 64 + l15) * 64;
  const int brow = (wn * 32 + l15) * 64;

  f32x4 acc00[4][2], acc01[4][2], acc10[4][2], acc11[4][2];  // [mh][nh]
#pragma unroll
  for (int mi = 0; mi < 4; mi++)
#pragma unroll
    for (int ni = 0; ni < 2; ni++) {
      acc00[mi][ni] = (f32x4){0.f, 0.f, 0.f, 0.f};
      acc01[mi][ni] = (f32x4){0.f, 0.f, 0.f, 0.f};
      acc10[mi][ni] = (f32x4){0.f, 0.f, 0.f, 0.f};
      acc11[mi][ni] = (f32x4){0.f, 0.f, 0.f, 0.f};
    }

  // prologue: tile 0, order Alo, Blo, Bhi, Ahi; publish {Alo, Blo}
  gl_lds16(A + oAlo[0], ls + 0 + ldW);
  gl_lds16(A + oAlo[1], ls + 4096 + ldW);
  gl_lds16(BdT + oBlo[0], ls + 16384 + ldW);
  gl_lds16(BdT + oBlo[1], ls + 16384 + 4096 + ldW);
  gl_lds16(BdT + oBhi[0], ls + 24576 + ldW);
  gl_lds16(BdT + oBhi[1], ls + 24576 + 4096 + ldW);
  gl_lds16(A + oAhi[0], ls + 8192 + ldW);
  gl_lds16(A + oAhi[1], ls + 8192 + 4096 + ldW);
  VMCNT4; BAR;

#pragma unroll 2
  for (int tt = 0; tt < I_ / BK; tt++) {
    const int p = tt & 1, q = p ^ 1;
    const ushort* sa = ls + p * SLOT;
    ushort* sq = ls + q * SLOT;
    const int kn = (tt + 1 < I_ / BK ? tt + 1 : tt) * BK;
    bf16x8 afL[4][2], afH[4][2], bfL[2][2], bfH[2][2];

    // ---- P0 ----
#pragma unroll
    for (int mi = 0; mi < 4; mi++) {
      afL[mi][0] = *(const bf16x8*)(sa + arow + mi * 1024 + s0);
      afL[mi][1] = *(const bf16x8*)(sa + arow + mi * 1024 + s1);
    }
#pragma unroll
    for (int ni = 0; ni < 2; ni++) {
      bfL[ni][0] = *(const bf16x8*)(sa + 16384 + brow + ni * 1024 + s0);
      bfL[ni][1] = *(const bf16x8*)(sa + 16384 + brow + ni * 1024 + s1);
    }
    gl_lds16(A + oAlo[0] + kn, sq + 0 + ldW);
    gl_lds16(A + oAlo[1] + kn, sq + 4096 + ldW);
    BAR;
    MFMA16(acc00, afL, bfL);
    VMCNT4; BAR;

    // ---- P1 ----
#pragma unroll
    for (int ni = 0; ni < 2; ni++) {
      bfH[ni][0] = *(const bf16x8*)(sa + 24576 + brow + ni * 1024 + s0);
      bfH[ni][1] = *(const bf16x8*)(sa + 24576 + brow + ni * 1024 + s1);
    }
    gl_lds16(BdT + oBlo[0] + kn, sq + 16384 + ldW);
    gl_lds16(BdT + oBlo[1] + kn, sq + 16384 + 4096 + ldW);
    BAR;
    MFMA16(acc01, afL, bfH);
    VMCNT4; BAR;

    // ---- P2 + P3 (merged tail) ----
#pragma unroll
    for (int mi = 0; mi < 4; mi++) {
      afH[mi][0] = *(const bf16x8*)(sa + 8192 + arow + mi * 1024 + s0);
      afH[mi][1] = *(const bf16x8*)(sa + 8192 + arow + mi * 1024 + s1);
    }
    gl_lds16(BdT + oBhi[0] + kn, sq + 24576 + ldW);
    gl_lds16(BdT + oBhi[1] + kn, sq + 24576 + 4096 + ldW);
    BAR;
    MFMA16(acc10, afH, bfL);
    gl_lds16(A + oAhi[0] + kn, sq + 8192 + ldW);
    gl_lds16(A + oAhi[1] + kn, sq + 8192 + 4096 + ldW);
    MFMA16(acc11, afH, bfH);
    VMCNT4; BAR;
  }

  const int cr = row0 + wm * 64 + (lk << 2);
  const int cc = n0 + wn * 32 + l15;
#pragma unroll
  for (int mh = 0; mh < 2; mh++)
#pragma unroll
    for (int mi = 0; mi < 4; mi++)
#pragma unroll
      for (int nh = 0; nh < 2; nh++)
#pragma unroll
        for (int ni = 0; ni < 2; ni++)
#pragma unroll
          for (int r = 0; r < 4; r++) {
            int row = cr + mh * 128 + mi * 16 + r;
            if (row < rowEnd) {
              float v = mh ? (nh ? acc11[mi][ni][r] : acc10[mi][ni][r])
                           : (nh ? acc01[mi][ni][r] : acc00[mi][ni][r]);
              Out[(size_t)row * H_ + cc + nh * 128 + ni * 16] = v;
            }
          }
}

extern "C" void kernel_launch(void* const* d_in, const int* in_sizes, int n_in,
                              void* d_out, int out_size, void* d_ws, size_t ws_size,
                              hipStream_t stream) {
  const float* hs = (const float*)d_in[0];
  const float* gw = (const float*)d_in[1];
  const float* uw = (const float*)d_in[2];
  const float* dw = (const float*)d_in[3];
  const int* gs = (const int*)d_in[4];
  float* out = (float*)d_out;

  ushort* hsb = (ushort*)d_ws;                       // [T,H]
  ushort* wgT = hsb + (size_t)T_ * H_;               // [E,I,H]
  ushort* wuT = wgT + (size_t)E_ * H_ * I_;          // [E,I,H]
  ushort* wdT = wuT + (size_t)E_ * H_ * I_;          // [E,H,I]
  ushort* hb  = wdT + (size_t)E_ * H_ * I_;          // [T,I]

  (void)hipFuncSetAttribute(reinterpret_cast<const void*>(gemm_gateup),
                            hipFuncAttributeMaxDynamicSharedMemorySize, 131072);
  (void)hipFuncSetAttribute(reinterpret_cast<const void*>(gemm_down),
                            hipFuncAttributeMaxDynamicSharedMemorySize, 131072);

  cvt_hs<<<((size_t)T_ * H_) / (256 * 8), 256, 0, stream>>>(hs, hsb);
  cvt_tr<<<dim3(I_ / 64, H_ / 64, E_), 256, 0, stream>>>(gw, wgT, H_, I_);
  cvt_tr<<<dim3(I_ / 64, H_ / 64, E_), 256, 0, stream>>>(uw, wuT, H_, I_);
  cvt_tr<<<dim3(H_ / 64, I_ / 64, E_), 256, 0, stream>>>(dw, wdT, I_, H_);

  gemm_gateup<<<dim3(MT_, I_ / 128), 512, 131072, stream>>>(hsb, wgT, wuT, gs, hb);
  gemm_down<<<dim3(MT_, H_ / 256), 512, 131072, stream>>>(hb, wdT, gs, out);
}